// Round 9
// baseline (205.330 us; speedup 1.0000x reference)
//
#include <hip/hip_runtime.h>
#include <math.h>

#define HW 16384
#define NPTS 1024
#define LOG_N 6.2383246250395075
#define RHO_C 0.09
#define SCALE_F 16384.0f
#define INV_SCALE2 3.725290298461914e-09  // 2^-28, exact
#define NTILES 36                          // 8x8 upper triangle

typedef _Float16 f16x8 __attribute__((ext_vector_type(8)));
typedef float f32x4 __attribute__((ext_vector_type(4)));

__device__ __forceinline__ void tri_map(int tt, int& ti, int& tj) {
  int a = 0, r = tt;
  while (r >= 8 - a) { r -= 8 - a; ++a; }
  ti = a; tj = a + r;
}

// ---------------------------------------------------------------------------
// Convert fp32 P=[nd;gt] (1024 x 16384) into scaled fp16 hi/lo split, stored
// fragment-native: hi2[slab = k64*2+kk][row(1024)][32]; a GEMM wave's MFMA
// fragment load (16 rows x 64B within one slab) is contiguous-per-lane ->
// coalesced global_load_dwordx4 direct to registers (no LDS).
// x_s = x*2^14 = hi + lo (exact residual; undone by 2^-28 in fp64 reduce).
// ---------------------------------------------------------------------------
__global__ __launch_bounds__(256)
void convert_split_k(const float* __restrict__ nd, const float* __restrict__ gt,
                     _Float16* __restrict__ hi2, _Float16* __restrict__ lo2) {
  const int tid = blockIdx.x * 256 + threadIdx.x;  // 0 .. 262143
  const int r = tid & 1023;
  const int k64 = tid >> 10;
  const float* __restrict__ src =
      (r < 512 ? nd + (size_t)r * HW : gt + (size_t)(r - 512) * HW) + k64 * 64;
  const size_t ob = ((size_t)k64 * 2048 + r) * 32;  // kk=0 slab; kk=1 at +1024*32
#pragma unroll
  for (int g = 0; g < 8; ++g) {
    const float4 v0 = *(const float4*)(src + g * 8);
    const float4 v1 = *(const float4*)(src + g * 8 + 4);
    const float x[8] = {v0.x, v0.y, v0.z, v0.w, v1.x, v1.y, v1.z, v1.w};
    f16x8 h, l;
#pragma unroll
    for (int j = 0; j < 8; ++j) {
      const float xs = x[j] * SCALE_F;
      const _Float16 hh = (_Float16)xs;
      h[j] = hh;
      l[j] = (_Float16)(xs - (float)hh);
    }
    const size_t o = ob + (size_t)(g >> 2) * (1024 * 32) + (g & 3) * 8;
    *(f16x8*)(hi2 + o) = h;
    *(f16x8*)(lo2 + o) = l;
  }
}

// ---------------------------------------------------------------------------
// Upper-triangle tiles only (G symmetric). 128x128 tile, 4 waves (2x2),
// 3-pass f16 split MFMA (hh + lh + hl). NO LDS: fragments loaded straight
// from global into registers (compiler-scheduled; round-8 showed explicit
// named-buffer pipelining regresses). Latency is hidden by TLP instead:
// split-K=28 -> 1008 blocks (~16 waves/CU), and a bijective XCD-chunked
// blockIdx swizzle puts all 36 tile-blocks of one k-chunk on one XCD so
// they stream the SAME 128KB slab data through that XCD's L2 together.
// ---------------------------------------------------------------------------
__global__ __launch_bounds__(256, 4)
void gemm_mfma_k(const _Float16* __restrict__ hi2, const _Float16* __restrict__ lo2,
                 float* __restrict__ part, int ns) {
  // bijective XCD-chunked swizzle (m204 form): XCD k gets a contiguous
  // lin-range; HW round-robins blocks to XCDs by dispatch index (b % 8).
  const int nwg = NTILES * ns;
  const int b = blockIdx.x;
  const int k8 = b & 7, i8 = b >> 3;
  const int q8 = nwg >> 3, r8 = nwg & 7;
  const int start = (k8 < r8) ? k8 * (q8 + 1) : r8 * (q8 + 1) + (k8 - r8) * q8;
  const int lin = start + i8;
  const int c = lin / NTILES, tt = lin - c * NTILES;

  int ti, tj;
  tri_map(tt, ti, tj);
  const int q = 256 / ns, rm = 256 - q * ns;
  const int kt0 = c * q + min(c, rm);
  const int nkt = q + (c < rm ? 1 : 0);
  const int t = threadIdx.x;
  const int lane = t & 63, w = t >> 6;
  const int wr = w >> 1, wc = w & 1;
  const int rlow = lane & 15, g0 = lane >> 4;

  f32x4 acc[4][4];
#pragma unroll
  for (int m = 0; m < 4; ++m)
#pragma unroll
    for (int n = 0; n < 4; ++n) acc[m][n] = (f32x4){0.f, 0.f, 0.f, 0.f};

  const size_t laneoff = (size_t)rlow * 32 + (size_t)g0 * 8;
  const size_t abase = (size_t)(ti * 128 + wr * 64) * 32 + laneoff;
  const size_t bbase = (size_t)(tj * 128 + wc * 64) * 32 + laneoff;

  for (int ks = 0; ks < nkt; ++ks) {
#pragma unroll
    for (int kk = 0; kk < 2; ++kk) {
      const size_t slab = ((size_t)(kt0 + ks) * 2 + kk) * (size_t)(1024 * 32);
      f16x8 fah[4], fal[4], fbh[4], fbl[4];
#pragma unroll
      for (int m = 0; m < 4; ++m) {
        fah[m] = *(const f16x8*)(hi2 + slab + abase + (size_t)m * 512);
        fal[m] = *(const f16x8*)(lo2 + slab + abase + (size_t)m * 512);
        fbh[m] = *(const f16x8*)(hi2 + slab + bbase + (size_t)m * 512);
        fbl[m] = *(const f16x8*)(lo2 + slab + bbase + (size_t)m * 512);
      }
#pragma unroll
      for (int m = 0; m < 4; ++m)
#pragma unroll
        for (int n = 0; n < 4; ++n) {
          acc[m][n] = __builtin_amdgcn_mfma_f32_16x16x32_f16(fah[m], fbh[n], acc[m][n], 0, 0, 0);
          acc[m][n] = __builtin_amdgcn_mfma_f32_16x16x32_f16(fal[m], fbh[n], acc[m][n], 0, 0, 0);
          acc[m][n] = __builtin_amdgcn_mfma_f32_16x16x32_f16(fah[m], fbl[n], acc[m][n], 0, 0, 0);
        }
    }
  }

  // C/D layout: col = lane&15, row = (lane>>4)*4 + q (m89-verified)
  float* __restrict__ dst = part + ((size_t)c * NTILES + tt) * 16384;
  const int c_locb = wc * 64 + rlow;
  const int r_locb = wr * 64 + g0 * 4;
#pragma unroll
  for (int m = 0; m < 4; ++m)
#pragma unroll
    for (int p = 0; p < 4; ++p) {
      const int rl = r_locb + m * 16 + p;
#pragma unroll
      for (int n = 0; n < 4; ++n)
        dst[rl * 128 + c_locb + n * 16] = acc[m][n][p];
    }
}

// ---------------------------------------------------------------------------
// Sum split-K partials (fp64), unscale, write G tile + mirrored tile (LDS
// transpose), extract diagonal. Grid: 36 tiles x 16 slabs of 8 rows = 576.
// ---------------------------------------------------------------------------
__global__ __launch_bounds__(256)
void reduce_tiles_k(const float* __restrict__ part, float* __restrict__ G,
                    float* __restrict__ diag, int nsplit) {
  __shared__ float sl[8][129];
  const int blk = blockIdx.x;  // 0..575
  const int tt = blk >> 4, s = blk & 15;
  int ti, tj;
  tri_map(tt, ti, tj);
  const int t = threadIdx.x;
  const int base_in = tt * 16384 + s * 1024;

  float vals[4];
#pragma unroll
  for (int j = 0; j < 4; ++j) {
    const int idx = j * 256 + t;  // 0..1023 within slab
    double a = 0.0;
    for (int c = 0; c < nsplit; ++c)
      a += (double)part[(size_t)c * (NTILES * 16384) + base_in + idx];
    vals[j] = (float)(a * INV_SCALE2);
  }
#pragma unroll
  for (int j = 0; j < 4; ++j) {
    const int idx = j * 256 + t;
    const int r = idx >> 7, cl = idx & 127;
    const int R = ti * 128 + s * 8 + r, C = tj * 128 + cl;
    G[(size_t)R * NPTS + C] = vals[j];
    if (R == C) diag[R] = vals[j];
    sl[r][cl] = vals[j];
  }
  if (ti == tj) return;
  __syncthreads();
#pragma unroll
  for (int j = 0; j < 4; ++j) {
    const int idx = j * 256 + t;
    const int r = idx & 7, cl = idx >> 3;
    G[(size_t)(tj * 128 + cl) * NPTS + ti * 128 + s * 8 + r] = sl[r][cl];
  }
}

// ---------------------------------------------------------------------------
// One symmetric Sinkhorn phase: 512 blocks x 4 waves; 1 wave = 1 row-task.
// pot layout: [0]=f_ba, [1]=g_ab, [2]=f_aa, [3]=g_bb (512 doubles each).
// ---------------------------------------------------------------------------
__global__ __launch_bounds__(256)
void sinkhorn_phase_k(const float* __restrict__ G, const float* __restrict__ diag,
                      const double* __restrict__ src, double* __restrict__ dst,
                      double eps, double inv_eps, double damp, int use_pot,
                      int do_avg) {
  const int w = threadIdx.x >> 6, lane = threadIdx.x & 63;
  const int id = blockIdx.x * 4 + w;  // 0..2047
  const int which = id >> 9, r = id & 511;
  int row_pt, col_base, pot_idx;
  if (which == 0)      { row_pt = r;       col_base = 512; pot_idx = 1; }
  else if (which == 1) { row_pt = 512 + r; col_base = 0;   pot_idx = 0; }
  else if (which == 2) { row_pt = r;       col_base = 0;   pot_idx = 2; }
  else                 { row_pt = 512 + r; col_base = 512; pot_idx = 3; }

  const double dr = (double)diag[row_pt];
  const double* __restrict__ pot = src + pot_idx * 512;
  const float* __restrict__ Grow = G + (size_t)row_pt * NPTS + col_base;
  const float* __restrict__ dcol = diag + col_base;

  double arg[8];
  double m = -1.0e300;
#pragma unroll
  for (int u = 0; u < 8; ++u) {
    const int j = lane + u * 64;
    const double C = 0.5 * (dr + (double)dcol[j]) - (double)Grow[j];
    const double p = use_pot ? pot[j] : 0.0;
    const double a = (p - C) * inv_eps - LOG_N;
    arg[u] = a;
    m = fmax(m, a);
  }
#pragma unroll
  for (int off = 32; off > 0; off >>= 1) m = fmax(m, __shfl_xor(m, off));
  double s = 0.0;
#pragma unroll
  for (int u = 0; u < 8; ++u) s += exp(arg[u] - m);
#pragma unroll
  for (int off = 32; off > 0; off >>= 1) s += __shfl_xor(s, off);
  if (lane == 0) {
    const double lse = m + log(s);
    const double val = -eps * lse * damp;
    dst[which * 512 + r] = do_avg ? 0.5 * (src[which * 512 + r] + val) : val;
  }
}

// ---------------------------------------------------------------------------
// Debiased unbalanced Sinkhorn loss.
// ---------------------------------------------------------------------------
__global__ __launch_bounds__(256)
void loss_k(const double* __restrict__ pot, float* __restrict__ out, int out_size,
            double w) {
  const int t = threadIdx.x;
  double s = 0.0;
  for (int i = t; i < 512; i += 256) {
    s += (exp(-pot[1024 + i] / RHO_C) - exp(-pot[i] / RHO_C)) +
         (exp(-pot[1536 + i] / RHO_C) - exp(-pot[512 + i] / RHO_C));
  }
#pragma unroll
  for (int off = 32; off > 0; off >>= 1) s += __shfl_xor(s, off);
  __shared__ double wsum[4];
  if ((t & 63) == 0) wsum[t >> 6] = s;
  __syncthreads();
  if (t == 0) {
    out[0] = (float)(w * (wsum[0] + wsum[1] + wsum[2] + wsum[3]) * (1.0 / 512.0));
    for (int i = 1; i < out_size; ++i) out[i] = 0.f;
  }
}

extern "C" void kernel_launch(void* const* d_in, const int* in_sizes, int n_in,
                              void* d_out, int out_size, void* d_ws, size_t ws_size,
                              hipStream_t stream) {
  const float* nd = (const float*)d_in[1];
  const float* gt = (const float*)d_in[2];
  float* out = (float*)d_out;
  char* ws = (char*)d_ws;

  const size_t GM = (size_t)NPTS * NPTS;     // 1M elems
  const size_t P16 = (size_t)NPTS * HW * 2;  // 32 MB per half
  int nsplit = 28;                            // 36*28 = 1008 blocks (~16 waves/CU)
  while (nsplit > 1 &&
         2 * P16 + (size_t)nsplit * NTILES * 16384 * 4 + GM * 4 + 65536 > ws_size)
    nsplit >>= 1;

  _Float16* hi2 = (_Float16*)ws;
  _Float16* lo2 = (_Float16*)(ws + P16);
  float* part = (float*)(ws + 2 * P16);
  const size_t partsz = (size_t)nsplit * NTILES * 16384 * 4;
  float* G = (float*)(ws + 2 * P16 + partsz);
  float* diag = (float*)(ws + 2 * P16 + partsz + GM * 4);
  double* pots = (double*)(ws + 2 * P16 + partsz + GM * 4 + 8192);

  convert_split_k<<<1024, 256, 0, stream>>>(nd, gt, hi2, lo2);
  gemm_mfma_k<<<NTILES * nsplit, 256, 0, stream>>>(hi2, lo2, part, nsplit);
  reduce_tiles_k<<<576, 256, 0, stream>>>(part, G, diag, nsplit);

  const double eps_list[9] = {1.0, 1.0, 0.25, 0.0625, 0.015625,
                              0.00390625, 0.0009765625, 0.000244140625, 1e-4};
  double* p0 = pots;
  double* p1 = pots + 2048;
  {  // init at eps0 = 1.0, no inner potentials, no averaging
    const double eps = 1.0, d = 1.0 / (1.0 + eps / RHO_C);
    sinkhorn_phase_k<<<512, 256, 0, stream>>>(G, diag, p1, p0, eps, 1.0 / eps, d, 0, 0);
  }
  double* src = p0;
  double* dst = p1;
  for (int k = 0; k < 9; ++k) {  // symmetric averaged updates
    const double eps = eps_list[k], d = 1.0 / (1.0 + eps / RHO_C);
    sinkhorn_phase_k<<<512, 256, 0, stream>>>(G, diag, src, dst, eps, 1.0 / eps, d, 1, 1);
    double* tmp = src; src = dst; dst = tmp;
  }
  {  // final extrapolation at blur^2, no averaging
    const double eps = 1e-4, d = 1.0 / (1.0 + eps / RHO_C);
    sinkhorn_phase_k<<<512, 256, 0, stream>>>(G, diag, src, dst, eps, 1.0 / eps, d, 1, 0);
    double* tmp = src; src = dst; dst = tmp;
  }
  loss_k<<<1, 256, 0, stream>>>(src, out, out_size, RHO_C + 1e-4 * 0.5);
}

// Round 10
// 188.138 us; speedup vs baseline: 1.0914x; 1.0914x over previous
//
#include <hip/hip_runtime.h>
#include <math.h>

#define HW 16384
#define NPTS 1024
#define LOG_N 6.2383246250395075
#define RHO_C 0.09
#define SCALE_F 16384.0f
#define INV_SCALE2 3.725290298461914e-09  // 2^-28, exact
#define NTILES 36                          // 8x8 upper triangle

typedef _Float16 f16x8 __attribute__((ext_vector_type(8)));
typedef float f32x4 __attribute__((ext_vector_type(4)));

__device__ __forceinline__ void tri_map(int tt, int& ti, int& tj) {
  int a = 0, r = tt;
  while (r >= 8 - a) { r -= 8 - a; ++a; }
  ti = a; tj = a + r;
}

// ---------------------------------------------------------------------------
// Convert fp32 P=[nd;gt] (1024 x 16384) into scaled fp16 hi/lo split, stored
// fragment-native: hi2[slab = k64*2+kk][row(1024)][32]; a GEMM wave's MFMA
// fragment load (16 rows x 64B within one slab) is contiguous-per-lane ->
// coalesced global_load_dwordx4 direct to registers (no LDS).
// ---------------------------------------------------------------------------
__global__ __launch_bounds__(256)
void convert_split_k(const float* __restrict__ nd, const float* __restrict__ gt,
                     _Float16* __restrict__ hi2, _Float16* __restrict__ lo2) {
  const int tid = blockIdx.x * 256 + threadIdx.x;  // 0 .. 262143
  const int r = tid & 1023;
  const int k64 = tid >> 10;
  const float* __restrict__ src =
      (r < 512 ? nd + (size_t)r * HW : gt + (size_t)(r - 512) * HW) + k64 * 64;
  const size_t ob = ((size_t)k64 * 2048 + r) * 32;  // kk=0 slab; kk=1 at +1024*32
#pragma unroll
  for (int g = 0; g < 8; ++g) {
    const float4 v0 = *(const float4*)(src + g * 8);
    const float4 v1 = *(const float4*)(src + g * 8 + 4);
    const float x[8] = {v0.x, v0.y, v0.z, v0.w, v1.x, v1.y, v1.z, v1.w};
    f16x8 h, l;
#pragma unroll
    for (int j = 0; j < 8; ++j) {
      const float xs = x[j] * SCALE_F;
      const _Float16 hh = (_Float16)xs;
      h[j] = hh;
      l[j] = (_Float16)(xs - (float)hh);
    }
    const size_t o = ob + (size_t)(g >> 2) * (1024 * 32) + (g & 3) * 8;
    *(f16x8*)(hi2 + o) = h;
    *(f16x8*)(lo2 + o) = l;
  }
}

// ---------------------------------------------------------------------------
// Upper-triangle tiles only (G symmetric). 128x128 tile, 4 waves (2x2),
// 3-pass f16 split MFMA. NO LDS. Round 7-9 showed the compiler serializes
// register-direct loads at 60 VGPR; here the K-loop is an EXPLICIT 2-deep
// inline-asm pipeline (AITER pattern): volatile global_load_dwordx4 into
// named frag buffers, counted s_waitcnt vmcnt(16) + sched_barrier(0)
// (guide rule 18), 48 MFMAs per slab hide the next slab's 16 loads.
// 36 x 14 = 504 blocks: one co-resident dispatch round; bijective
// XCD-chunked swizzle keeps each k-chunk's slab stream on one XCD's L2
// (round 9: FETCH 234 -> 37 MB).
// ---------------------------------------------------------------------------
#define ISSUE16(AH, AL, BH, BL, SLABIDX)                                        \
  {                                                                             \
    const size_t soff_ = (size_t)(SLABIDX) * 32768;                             \
    const _Float16* pah_ = hi2 + soff_ + abase;                                 \
    const _Float16* pal_ = lo2 + soff_ + abase;                                 \
    const _Float16* pbh_ = hi2 + soff_ + bbase;                                 \
    const _Float16* pbl_ = lo2 + soff_ + bbase;                                 \
    _Pragma("unroll")                                                           \
    for (int m_ = 0; m_ < 4; ++m_) {                                            \
      asm volatile("global_load_dwordx4 %0, %1, off"                            \
                   : "=v"(AH[m_]) : "v"(pah_ + m_ * 512));                      \
      asm volatile("global_load_dwordx4 %0, %1, off"                            \
                   : "=v"(AL[m_]) : "v"(pal_ + m_ * 512));                      \
      asm volatile("global_load_dwordx4 %0, %1, off"                            \
                   : "=v"(BH[m_]) : "v"(pbh_ + m_ * 512));                      \
      asm volatile("global_load_dwordx4 %0, %1, off"                            \
                   : "=v"(BL[m_]) : "v"(pbl_ + m_ * 512));                      \
    }                                                                           \
  }

#define WAIT16                                                                  \
  asm volatile("s_waitcnt vmcnt(16)" ::: "memory");                             \
  __builtin_amdgcn_sched_barrier(0);

#define MFMA48(AH, AL, BH, BL)                                                  \
  _Pragma("unroll")                                                             \
  for (int m_ = 0; m_ < 4; ++m_)                                                \
    _Pragma("unroll")                                                           \
    for (int n_ = 0; n_ < 4; ++n_) {                                            \
      acc[m_][n_] = __builtin_amdgcn_mfma_f32_16x16x32_f16(AH[m_], BH[n_],      \
                                                           acc[m_][n_], 0, 0, 0); \
      acc[m_][n_] = __builtin_amdgcn_mfma_f32_16x16x32_f16(AL[m_], BH[n_],      \
                                                           acc[m_][n_], 0, 0, 0); \
      acc[m_][n_] = __builtin_amdgcn_mfma_f32_16x16x32_f16(AH[m_], BL[n_],      \
                                                           acc[m_][n_], 0, 0, 0); \
    }

__global__ __launch_bounds__(256, 2)
void gemm_mfma_k(const _Float16* __restrict__ hi2, const _Float16* __restrict__ lo2,
                 float* __restrict__ part, int ns) {
  // bijective XCD-chunked swizzle (m204 form)
  const int nwg = NTILES * ns;
  const int b = blockIdx.x;
  const int k8 = b & 7, i8 = b >> 3;
  const int q8 = nwg >> 3, r8 = nwg & 7;
  const int start = (k8 < r8) ? k8 * (q8 + 1) : r8 * (q8 + 1) + (k8 - r8) * q8;
  const int lin = start + i8;
  const int c = lin / NTILES, tt = lin - c * NTILES;

  int ti, tj;
  tri_map(tt, ti, tj);
  const int q = 256 / ns, rm = 256 - q * ns;
  const int kt0 = c * q + (c < rm ? c : rm);
  const int nkt = q + (c < rm ? 1 : 0);
  const int t = threadIdx.x;
  const int lane = t & 63, w = t >> 6;
  const int wr = w >> 1, wc = w & 1;
  const int rlow = lane & 15, g0 = lane >> 4;

  f32x4 acc[4][4];
#pragma unroll
  for (int m = 0; m < 4; ++m)
#pragma unroll
    for (int n = 0; n < 4; ++n) acc[m][n] = (f32x4){0.f, 0.f, 0.f, 0.f};

  const size_t laneoff = (size_t)rlow * 32 + (size_t)g0 * 8;
  const size_t abase = (size_t)(ti * 128 + wr * 64) * 32 + laneoff;
  const size_t bbase = (size_t)(tj * 128 + wc * 64) * 32 + laneoff;

  const int s0 = 2 * kt0, sN = 2 * (kt0 + nkt);  // slab count 2*nkt is even

  f16x8 eah[4], eal[4], ebh[4], ebl[4];
  f16x8 oah[4], oal[4], obh[4], obl[4];

  ISSUE16(eah, eal, ebh, ebl, s0);          // 16 outstanding
  ISSUE16(oah, oal, obh, obl, s0 + 1);      // 32 outstanding
  for (int s = s0; s < sN; s += 2) {
    WAIT16;                                  // even buffer ready
    MFMA48(eah, eal, ebh, ebl);
    { const int nx = (s + 2 < sN) ? s + 2 : s0; ISSUE16(eah, eal, ebh, ebl, nx); }
    WAIT16;                                  // odd buffer ready
    MFMA48(oah, oal, obh, obl);
    { const int nx = (s + 3 < sN) ? s + 3 : s0; ISSUE16(oah, oal, obh, obl, nx); }
  }
  asm volatile("s_waitcnt vmcnt(0)" ::: "memory");
  __builtin_amdgcn_sched_barrier(0);

  // C/D layout: col = lane&15, row = (lane>>4)*4 + q (m89-verified)
  float* __restrict__ dst = part + ((size_t)c * NTILES + tt) * 16384;
  const int c_locb = wc * 64 + rlow;
  const int r_locb = wr * 64 + g0 * 4;
#pragma unroll
  for (int m = 0; m < 4; ++m)
#pragma unroll
    for (int p = 0; p < 4; ++p) {
      const int rl = r_locb + m * 16 + p;
#pragma unroll
      for (int n = 0; n < 4; ++n)
        dst[rl * 128 + c_locb + n * 16] = acc[m][n][p];
    }
}

// ---------------------------------------------------------------------------
// Sum split-K partials (fp64), unscale, write G tile + mirrored tile (LDS
// transpose), extract diagonal. Grid: 36 tiles x 16 slabs of 8 rows = 576.
// ---------------------------------------------------------------------------
__global__ __launch_bounds__(256)
void reduce_tiles_k(const float* __restrict__ part, float* __restrict__ G,
                    float* __restrict__ diag, int nsplit) {
  __shared__ float sl[8][129];
  const int blk = blockIdx.x;  // 0..575
  const int tt = blk >> 4, s = blk & 15;
  int ti, tj;
  tri_map(tt, ti, tj);
  const int t = threadIdx.x;
  const int base_in = tt * 16384 + s * 1024;

  float vals[4];
#pragma unroll
  for (int j = 0; j < 4; ++j) {
    const int idx = j * 256 + t;  // 0..1023 within slab
    double a = 0.0;
    for (int c = 0; c < nsplit; ++c)
      a += (double)part[(size_t)c * (NTILES * 16384) + base_in + idx];
    vals[j] = (float)(a * INV_SCALE2);
  }
#pragma unroll
  for (int j = 0; j < 4; ++j) {
    const int idx = j * 256 + t;
    const int r = idx >> 7, cl = idx & 127;
    const int R = ti * 128 + s * 8 + r, C = tj * 128 + cl;
    G[(size_t)R * NPTS + C] = vals[j];
    if (R == C) diag[R] = vals[j];
    sl[r][cl] = vals[j];
  }
  if (ti == tj) return;
  __syncthreads();
#pragma unroll
  for (int j = 0; j < 4; ++j) {
    const int idx = j * 256 + t;
    const int r = idx & 7, cl = idx >> 3;
    G[(size_t)(tj * 128 + cl) * NPTS + ti * 128 + s * 8 + r] = sl[r][cl];
  }
}

// ---------------------------------------------------------------------------
// One symmetric Sinkhorn phase: 512 blocks x 4 waves; 1 wave = 1 row-task.
// pot layout: [0]=f_ba, [1]=g_ab, [2]=f_aa, [3]=g_bb (512 doubles each).
// ---------------------------------------------------------------------------
__global__ __launch_bounds__(256)
void sinkhorn_phase_k(const float* __restrict__ G, const float* __restrict__ diag,
                      const double* __restrict__ src, double* __restrict__ dst,
                      double eps, double inv_eps, double damp, int use_pot,
                      int do_avg) {
  const int w = threadIdx.x >> 6, lane = threadIdx.x & 63;
  const int id = blockIdx.x * 4 + w;  // 0..2047
  const int which = id >> 9, r = id & 511;
  int row_pt, col_base, pot_idx;
  if (which == 0)      { row_pt = r;       col_base = 512; pot_idx = 1; }
  else if (which == 1) { row_pt = 512 + r; col_base = 0;   pot_idx = 0; }
  else if (which == 2) { row_pt = r;       col_base = 0;   pot_idx = 2; }
  else                 { row_pt = 512 + r; col_base = 512; pot_idx = 3; }

  const double dr = (double)diag[row_pt];
  const double* __restrict__ pot = src + pot_idx * 512;
  const float* __restrict__ Grow = G + (size_t)row_pt * NPTS + col_base;
  const float* __restrict__ dcol = diag + col_base;

  double arg[8];
  double m = -1.0e300;
#pragma unroll
  for (int u = 0; u < 8; ++u) {
    const int j = lane + u * 64;
    const double C = 0.5 * (dr + (double)dcol[j]) - (double)Grow[j];
    const double p = use_pot ? pot[j] : 0.0;
    const double a = (p - C) * inv_eps - LOG_N;
    arg[u] = a;
    m = fmax(m, a);
  }
#pragma unroll
  for (int off = 32; off > 0; off >>= 1) m = fmax(m, __shfl_xor(m, off));
  double s = 0.0;
#pragma unroll
  for (int u = 0; u < 8; ++u) s += exp(arg[u] - m);
#pragma unroll
  for (int off = 32; off > 0; off >>= 1) s += __shfl_xor(s, off);
  if (lane == 0) {
    const double lse = m + log(s);
    const double val = -eps * lse * damp;
    dst[which * 512 + r] = do_avg ? 0.5 * (src[which * 512 + r] + val) : val;
  }
}

// ---------------------------------------------------------------------------
// Debiased unbalanced Sinkhorn loss.
// ---------------------------------------------------------------------------
__global__ __launch_bounds__(256)
void loss_k(const double* __restrict__ pot, float* __restrict__ out, int out_size,
            double w) {
  const int t = threadIdx.x;
  double s = 0.0;
  for (int i = t; i < 512; i += 256) {
    s += (exp(-pot[1024 + i] / RHO_C) - exp(-pot[i] / RHO_C)) +
         (exp(-pot[1536 + i] / RHO_C) - exp(-pot[512 + i] / RHO_C));
  }
#pragma unroll
  for (int off = 32; off > 0; off >>= 1) s += __shfl_xor(s, off);
  __shared__ double wsum[4];
  if ((t & 63) == 0) wsum[t >> 6] = s;
  __syncthreads();
  if (t == 0) {
    out[0] = (float)(w * (wsum[0] + wsum[1] + wsum[2] + wsum[3]) * (1.0 / 512.0));
    for (int i = 1; i < out_size; ++i) out[i] = 0.f;
  }
}

extern "C" void kernel_launch(void* const* d_in, const int* in_sizes, int n_in,
                              void* d_out, int out_size, void* d_ws, size_t ws_size,
                              hipStream_t stream) {
  const float* nd = (const float*)d_in[1];
  const float* gt = (const float*)d_in[2];
  float* out = (float*)d_out;
  char* ws = (char*)d_ws;

  const size_t GM = (size_t)NPTS * NPTS;     // 1M elems
  const size_t P16 = (size_t)NPTS * HW * 2;  // 32 MB per half
  int nsplit = 14;                            // 36*14 = 504 blocks: no tail, %8==0
  while (nsplit > 1 &&
         2 * P16 + (size_t)nsplit * NTILES * 16384 * 4 + GM * 4 + 65536 > ws_size)
    nsplit >>= 1;

  _Float16* hi2 = (_Float16*)ws;
  _Float16* lo2 = (_Float16*)(ws + P16);
  float* part = (float*)(ws + 2 * P16);
  const size_t partsz = (size_t)nsplit * NTILES * 16384 * 4;
  float* G = (float*)(ws + 2 * P16 + partsz);
  float* diag = (float*)(ws + 2 * P16 + partsz + GM * 4);
  double* pots = (double*)(ws + 2 * P16 + partsz + GM * 4 + 8192);

  convert_split_k<<<1024, 256, 0, stream>>>(nd, gt, hi2, lo2);
  gemm_mfma_k<<<NTILES * nsplit, 256, 0, stream>>>(hi2, lo2, part, nsplit);
  reduce_tiles_k<<<576, 256, 0, stream>>>(part, G, diag, nsplit);

  const double eps_list[9] = {1.0, 1.0, 0.25, 0.0625, 0.015625,
                              0.00390625, 0.0009765625, 0.000244140625, 1e-4};
  double* p0 = pots;
  double* p1 = pots + 2048;
  {  // init at eps0 = 1.0, no inner potentials, no averaging
    const double eps = 1.0, d = 1.0 / (1.0 + eps / RHO_C);
    sinkhorn_phase_k<<<512, 256, 0, stream>>>(G, diag, p1, p0, eps, 1.0 / eps, d, 0, 0);
  }
  double* src = p0;
  double* dst = p1;
  for (int k = 0; k < 9; ++k) {  // symmetric averaged updates
    const double eps = eps_list[k], d = 1.0 / (1.0 + eps / RHO_C);
    sinkhorn_phase_k<<<512, 256, 0, stream>>>(G, diag, src, dst, eps, 1.0 / eps, d, 1, 1);
    double* tmp = src; src = dst; dst = tmp;
  }
  {  // final extrapolation at blur^2, no averaging
    const double eps = 1e-4, d = 1.0 / (1.0 + eps / RHO_C);
    sinkhorn_phase_k<<<512, 256, 0, stream>>>(G, diag, src, dst, eps, 1.0 / eps, d, 1, 0);
    double* tmp = src; src = dst; dst = tmp;
  }
  loss_k<<<1, 256, 0, stream>>>(src, out, out_size, RHO_C + 1e-4 * 0.5);
}

// Round 11
// 160.091 us; speedup vs baseline: 1.2826x; 1.1752x over previous
//
#include <hip/hip_runtime.h>
#include <math.h>

#define HW 16384
#define NPTS 1024
#define LOG_N 6.2383246250395075
#define RHO_C 0.09
#define SCALE_F 16384.0f
#define INV_SCALE2 3.725290298461914e-09  // 2^-28, exact
#define NTILES 36                          // 8x8 upper triangle

typedef _Float16 f16x8 __attribute__((ext_vector_type(8)));
typedef float f32x4 __attribute__((ext_vector_type(4)));

typedef __attribute__((address_space(1))) const void gvoid_t;
typedef __attribute__((address_space(3))) void svoid_t;

__device__ __forceinline__ void tri_map(int tt, int& ti, int& tj) {
  int a = 0, r = tt;
  while (r >= 8 - a) { r -= 8 - a; ++a; }
  ti = a; tj = a + r;
}

// ---------------------------------------------------------------------------
// Convert fp32 P=[nd;gt] (1024 x 16384) into scaled fp16 hi/lo split, stored
// K-tiled: hi_t[k64][row][64], 8-elem groups pre-swizzled by g ^ (row&7) so
// the GEMM's linear global_load_lds yields a conflict-free LDS image
// (proven 0-conflict in rounds 2-6).
// ---------------------------------------------------------------------------
__global__ __launch_bounds__(256)
void convert_split_k(const float* __restrict__ nd, const float* __restrict__ gt,
                     _Float16* __restrict__ hi_t, _Float16* __restrict__ lo_t) {
  const int tid = blockIdx.x * 256 + threadIdx.x;  // 0 .. 262143
  const int r = tid & 1023;
  const int k64 = tid >> 10;
  const float* __restrict__ src =
      (r < 512 ? nd + (size_t)r * HW : gt + (size_t)(r - 512) * HW) + k64 * 64;
  const size_t obase = ((size_t)k64 * 1024 + r) * 64;
  const int sw = r & 7;
#pragma unroll
  for (int g = 0; g < 8; ++g) {
    const float4 v0 = *(const float4*)(src + g * 8);
    const float4 v1 = *(const float4*)(src + g * 8 + 4);
    const float x[8] = {v0.x, v0.y, v0.z, v0.w, v1.x, v1.y, v1.z, v1.w};
    f16x8 h, l;
#pragma unroll
    for (int j = 0; j < 8; ++j) {
      const float xs = x[j] * SCALE_F;
      const _Float16 hh = (_Float16)xs;
      h[j] = hh;
      l[j] = (_Float16)(xs - (float)hh);
    }
    *(f16x8*)(hi_t + obase + (size_t)(g ^ sw) * 8) = h;
    *(f16x8*)(lo_t + obase + (size_t)(g ^ sw) * 8) = l;
  }
}

// ---------------------------------------------------------------------------
// Upper-triangle tiles (G symmetric). 128x128 tile, 8 waves (2x4), BK=64,
// 3-pass f16 split MFMA. T3 "2-phase" schedule: double-buffered 2x64KB LDS,
// ONE barrier per K-step:
//   STAGE(next) ; sched_barrier ; ds_read(cur) ; MFMA ; __syncthreads()
// The next tile's 64 global_load_lds are in flight across the whole step's
// ds_read+MFMA window (~1900 cyc >> 600 cyc latency + 1024 cyc BW), unlike
// rounds 2-10 where staging was drained before compute (the m97 ceiling).
// nsplit=7 -> 252 blocks = one co-resident round at 1 block/CU (128KB LDS).
// ---------------------------------------------------------------------------
#define STAGE(BUF, KT)                                                          \
  {                                                                             \
    const size_t tb_ = (size_t)(KT) * 65536;                                    \
    const size_t ga_ = tb_ + (size_t)ti * 8192 + w * 1024 + lane * 8;           \
    const size_t gb_ = tb_ + (size_t)tj * 8192 + w * 1024 + lane * 8;           \
    _Float16* lb_ = lds + (BUF) * 32768 + w * 1024;                             \
    __builtin_amdgcn_global_load_lds((gvoid_t*)(hi_t + ga_), (svoid_t*)(lb_), 16, 0, 0);                   \
    __builtin_amdgcn_global_load_lds((gvoid_t*)(hi_t + ga_ + 512), (svoid_t*)(lb_ + 512), 16, 0, 0);       \
    __builtin_amdgcn_global_load_lds((gvoid_t*)(lo_t + ga_), (svoid_t*)(lb_ + 8192), 16, 0, 0);            \
    __builtin_amdgcn_global_load_lds((gvoid_t*)(lo_t + ga_ + 512), (svoid_t*)(lb_ + 8704), 16, 0, 0);      \
    __builtin_amdgcn_global_load_lds((gvoid_t*)(hi_t + gb_), (svoid_t*)(lb_ + 16384), 16, 0, 0);           \
    __builtin_amdgcn_global_load_lds((gvoid_t*)(hi_t + gb_ + 512), (svoid_t*)(lb_ + 16896), 16, 0, 0);     \
    __builtin_amdgcn_global_load_lds((gvoid_t*)(lo_t + gb_), (svoid_t*)(lb_ + 24576), 16, 0, 0);           \
    __builtin_amdgcn_global_load_lds((gvoid_t*)(lo_t + gb_ + 512), (svoid_t*)(lb_ + 25088), 16, 0, 0);     \
  }

__global__ __launch_bounds__(512, 2)
void gemm_mfma_k(const _Float16* __restrict__ hi_t, const _Float16* __restrict__ lo_t,
                 float* __restrict__ part, int ns) {
  extern __shared__ _Float16 lds[];  // [2 buf][4 arr: Ahi,Alo,Bhi,Blo][8192]

  // bijective XCD-chunked swizzle (m204 form)
  const int nwg = NTILES * ns;
  const int b = blockIdx.x;
  const int k8 = b & 7, i8 = b >> 3;
  const int q8 = nwg >> 3, r8 = nwg & 7;
  const int start = (k8 < r8) ? k8 * (q8 + 1) : r8 * (q8 + 1) + (k8 - r8) * q8;
  const int lin = start + i8;
  const int c = lin / NTILES, tt = lin - c * NTILES;

  int ti, tj;
  tri_map(tt, ti, tj);
  const int q = 256 / ns, rm = 256 - q * ns;
  const int kt0 = c * q + (c < rm ? c : rm);
  const int nkt = q + (c < rm ? 1 : 0);
  const int t = threadIdx.x;
  const int lane = t & 63, w = t >> 6;  // 8 waves
  const int wr = w >> 2, wc = w & 3;    // 2 x 4 wave grid
  const int rlow = lane & 15, g0 = lane >> 4;
  const int sw = rlow & 7;

  f32x4 acc[4][2];
#pragma unroll
  for (int m = 0; m < 4; ++m)
#pragma unroll
    for (int n = 0; n < 2; ++n) acc[m][n] = (f32x4){0.f, 0.f, 0.f, 0.f};

  STAGE(0, kt0);
  __syncthreads();

  int cur = 0;
  for (int ks = 0; ks < nkt; ++ks) {
    if (ks + 1 < nkt) STAGE(cur ^ 1, kt0 + ks + 1);
    __builtin_amdgcn_sched_barrier(0);  // pin stages before reads/MFMA

    const _Float16* __restrict__ bb = lds + cur * 32768;
    f16x8 ah[2][4], al[2][4], bh[2][2], bl[2][2];
#pragma unroll
    for (int kk = 0; kk < 2; ++kk) {
      const int pe = ((kk * 4 + g0) ^ sw) * 8;
#pragma unroll
      for (int m = 0; m < 4; ++m) {
        const int ra = wr * 64 + m * 16 + rlow;
        ah[kk][m] = *(const f16x8*)(bb + ra * 64 + pe);
        al[kk][m] = *(const f16x8*)(bb + 8192 + ra * 64 + pe);
      }
#pragma unroll
      for (int n = 0; n < 2; ++n) {
        const int rb = wc * 32 + n * 16 + rlow;
        bh[kk][n] = *(const f16x8*)(bb + 16384 + rb * 64 + pe);
        bl[kk][n] = *(const f16x8*)(bb + 24576 + rb * 64 + pe);
      }
    }

    __builtin_amdgcn_s_setprio(1);
#pragma unroll
    for (int kk = 0; kk < 2; ++kk)
#pragma unroll
      for (int m = 0; m < 4; ++m)
#pragma unroll
        for (int n = 0; n < 2; ++n) {
          acc[m][n] = __builtin_amdgcn_mfma_f32_16x16x32_f16(ah[kk][m], bh[kk][n], acc[m][n], 0, 0, 0);
          acc[m][n] = __builtin_amdgcn_mfma_f32_16x16x32_f16(al[kk][m], bh[kk][n], acc[m][n], 0, 0, 0);
          acc[m][n] = __builtin_amdgcn_mfma_f32_16x16x32_f16(ah[kk][m], bl[kk][n], acc[m][n], 0, 0, 0);
        }
    __builtin_amdgcn_s_setprio(0);
    __syncthreads();  // drains stage (vmcnt0) + read-done for both buffers
    cur ^= 1;
  }

  // C/D layout: col = lane&15, row = (lane>>4)*4 + p (m89-verified)
  float* __restrict__ dst = part + ((size_t)c * NTILES + tt) * 16384;
  const int clb = wc * 32 + rlow;
  const int rlb = wr * 64 + g0 * 4;
#pragma unroll
  for (int m = 0; m < 4; ++m)
#pragma unroll
    for (int p = 0; p < 4; ++p) {
      const int rl = rlb + m * 16 + p;
#pragma unroll
      for (int n = 0; n < 2; ++n)
        dst[rl * 128 + clb + n * 16] = acc[m][n][p];
    }
}

// ---------------------------------------------------------------------------
// Sum split-K partials (fp64), unscale, write G tile + mirrored tile (LDS
// transpose), extract diagonal. Grid: 36 tiles x 16 slabs of 8 rows = 576.
// ---------------------------------------------------------------------------
__global__ __launch_bounds__(256)
void reduce_tiles_k(const float* __restrict__ part, float* __restrict__ G,
                    float* __restrict__ diag, int nsplit) {
  __shared__ float sl[8][129];
  const int blk = blockIdx.x;  // 0..575
  const int tt = blk >> 4, s = blk & 15;
  int ti, tj;
  tri_map(tt, ti, tj);
  const int t = threadIdx.x;
  const int base_in = tt * 16384 + s * 1024;

  float vals[4];
#pragma unroll
  for (int j = 0; j < 4; ++j) {
    const int idx = j * 256 + t;  // 0..1023 within slab
    double a = 0.0;
    for (int c = 0; c < nsplit; ++c)
      a += (double)part[(size_t)c * (NTILES * 16384) + base_in + idx];
    vals[j] = (float)(a * INV_SCALE2);
  }
#pragma unroll
  for (int j = 0; j < 4; ++j) {
    const int idx = j * 256 + t;
    const int r = idx >> 7, cl = idx & 127;
    const int R = ti * 128 + s * 8 + r, C = tj * 128 + cl;
    G[(size_t)R * NPTS + C] = vals[j];
    if (R == C) diag[R] = vals[j];
    sl[r][cl] = vals[j];
  }
  if (ti == tj) return;
  __syncthreads();
#pragma unroll
  for (int j = 0; j < 4; ++j) {
    const int idx = j * 256 + t;
    const int r = idx & 7, cl = idx >> 3;
    G[(size_t)(tj * 128 + cl) * NPTS + ti * 128 + s * 8 + r] = sl[r][cl];
  }
}

// ---------------------------------------------------------------------------
// One symmetric Sinkhorn phase: 512 blocks x 4 waves; 1 wave = 1 row-task.
// pot layout: [0]=f_ba, [1]=g_ab, [2]=f_aa, [3]=g_bb (512 doubles each).
// ---------------------------------------------------------------------------
__global__ __launch_bounds__(256)
void sinkhorn_phase_k(const float* __restrict__ G, const float* __restrict__ diag,
                      const double* __restrict__ src, double* __restrict__ dst,
                      double eps, double inv_eps, double damp, int use_pot,
                      int do_avg) {
  const int w = threadIdx.x >> 6, lane = threadIdx.x & 63;
  const int id = blockIdx.x * 4 + w;  // 0..2047
  const int which = id >> 9, r = id & 511;
  int row_pt, col_base, pot_idx;
  if (which == 0)      { row_pt = r;       col_base = 512; pot_idx = 1; }
  else if (which == 1) { row_pt = 512 + r; col_base = 0;   pot_idx = 0; }
  else if (which == 2) { row_pt = r;       col_base = 0;   pot_idx = 2; }
  else                 { row_pt = 512 + r; col_base = 512; pot_idx = 3; }

  const double dr = (double)diag[row_pt];
  const double* __restrict__ pot = src + pot_idx * 512;
  const float* __restrict__ Grow = G + (size_t)row_pt * NPTS + col_base;
  const float* __restrict__ dcol = diag + col_base;

  double arg[8];
  double m = -1.0e300;
#pragma unroll
  for (int u = 0; u < 8; ++u) {
    const int j = lane + u * 64;
    const double C = 0.5 * (dr + (double)dcol[j]) - (double)Grow[j];
    const double p = use_pot ? pot[j] : 0.0;
    const double a = (p - C) * inv_eps - LOG_N;
    arg[u] = a;
    m = fmax(m, a);
  }
#pragma unroll
  for (int off = 32; off > 0; off >>= 1) m = fmax(m, __shfl_xor(m, off));
  double s = 0.0;
#pragma unroll
  for (int u = 0; u < 8; ++u) s += exp(arg[u] - m);
#pragma unroll
  for (int off = 32; off > 0; off >>= 1) s += __shfl_xor(s, off);
  if (lane == 0) {
    const double lse = m + log(s);
    const double val = -eps * lse * damp;
    dst[which * 512 + r] = do_avg ? 0.5 * (src[which * 512 + r] + val) : val;
  }
}

// ---------------------------------------------------------------------------
// Debiased unbalanced Sinkhorn loss.
// ---------------------------------------------------------------------------
__global__ __launch_bounds__(256)
void loss_k(const double* __restrict__ pot, float* __restrict__ out, int out_size,
            double w) {
  const int t = threadIdx.x;
  double s = 0.0;
  for (int i = t; i < 512; i += 256) {
    s += (exp(-pot[1024 + i] / RHO_C) - exp(-pot[i] / RHO_C)) +
         (exp(-pot[1536 + i] / RHO_C) - exp(-pot[512 + i] / RHO_C));
  }
#pragma unroll
  for (int off = 32; off > 0; off >>= 1) s += __shfl_xor(s, off);
  __shared__ double wsum[4];
  if ((t & 63) == 0) wsum[t >> 6] = s;
  __syncthreads();
  if (t == 0) {
    out[0] = (float)(w * (wsum[0] + wsum[1] + wsum[2] + wsum[3]) * (1.0 / 512.0));
    for (int i = 1; i < out_size; ++i) out[i] = 0.f;
  }
}

extern "C" void kernel_launch(void* const* d_in, const int* in_sizes, int n_in,
                              void* d_out, int out_size, void* d_ws, size_t ws_size,
                              hipStream_t stream) {
  const float* nd = (const float*)d_in[1];
  const float* gt = (const float*)d_in[2];
  float* out = (float*)d_out;
  char* ws = (char*)d_ws;

  const size_t GM = (size_t)NPTS * NPTS;     // 1M elems
  const size_t P16 = (size_t)NPTS * HW * 2;  // 32 MB per half
  int nsplit = 7;                             // 36*7 = 252 blocks @ 1/CU: 1 round
  while (nsplit > 1 &&
         2 * P16 + (size_t)nsplit * NTILES * 16384 * 4 + GM * 4 + 65536 > ws_size)
    nsplit >>= 1;

  _Float16* hi_t = (_Float16*)ws;
  _Float16* lo_t = (_Float16*)(ws + P16);
  float* part = (float*)(ws + 2 * P16);
  const size_t partsz = (size_t)nsplit * NTILES * 16384 * 4;
  float* G = (float*)(ws + 2 * P16 + partsz);
  float* diag = (float*)(ws + 2 * P16 + partsz + GM * 4);
  double* pots = (double*)(ws + 2 * P16 + partsz + GM * 4 + 8192);

  hipFuncSetAttribute((const void*)gemm_mfma_k,
                      hipFuncAttributeMaxDynamicSharedMemorySize, 131072);

  convert_split_k<<<1024, 256, 0, stream>>>(nd, gt, hi_t, lo_t);
  gemm_mfma_k<<<NTILES * nsplit, 512, 131072, stream>>>(hi_t, lo_t, part, nsplit);
  reduce_tiles_k<<<576, 256, 0, stream>>>(part, G, diag, nsplit);

  const double eps_list[9] = {1.0, 1.0, 0.25, 0.0625, 0.015625,
                              0.00390625, 0.0009765625, 0.000244140625, 1e-4};
  double* p0 = pots;
  double* p1 = pots + 2048;
  {  // init at eps0 = 1.0, no inner potentials, no averaging
    const double eps = 1.0, d = 1.0 / (1.0 + eps / RHO_C);
    sinkhorn_phase_k<<<512, 256, 0, stream>>>(G, diag, p1, p0, eps, 1.0 / eps, d, 0, 0);
  }
  double* src = p0;
  double* dst = p1;
  for (int k = 0; k < 9; ++k) {  // symmetric averaged updates
    const double eps = eps_list[k], d = 1.0 / (1.0 + eps / RHO_C);
    sinkhorn_phase_k<<<512, 256, 0, stream>>>(G, diag, src, dst, eps, 1.0 / eps, d, 1, 1);
    double* tmp = src; src = dst; dst = tmp;
  }
  {  // final extrapolation at blur^2, no averaging
    const double eps = 1e-4, d = 1.0 / (1.0 + eps / RHO_C);
    sinkhorn_phase_k<<<512, 256, 0, stream>>>(G, diag, src, dst, eps, 1.0 / eps, d, 1, 0);
    double* tmp = src; src = dst; dst = tmp;
  }
  loss_k<<<1, 256, 0, stream>>>(src, out, out_size, RHO_C + 1e-4 * 0.5);
}

// Round 12
// 140.884 us; speedup vs baseline: 1.4574x; 1.1363x over previous
//
#include <hip/hip_runtime.h>
#include <math.h>

#define HW 16384
#define NPTS 1024
#define LOG_N 6.2383246250395075
#define RHO_C 0.09
#define SCALE_F 16384.0f
#define INV_SCALE2 3.725290298461914e-09  // 2^-28, exact
#define NTILES 36                          // 8x8 upper triangle

typedef _Float16 f16x8 __attribute__((ext_vector_type(8)));
typedef float f32x4 __attribute__((ext_vector_type(4)));

typedef __attribute__((address_space(1))) const void gvoid_t;
typedef __attribute__((address_space(3))) void svoid_t;

__device__ __forceinline__ void tri_map(int tt, int& ti, int& tj) {
  int a = 0, r = tt;
  while (r >= 8 - a) { r -= 8 - a; ++a; }
  ti = a; tj = a + r;
}

// ---------------------------------------------------------------------------
// Convert fp32 P=[nd;gt] (1024 x 16384) into scaled fp16 hi/lo split, stored
// K-tiled: hi_t[k64][row][64], groups pre-swizzled by g ^ (row&7) (GEMM's
// conflict-free LDS image). Round-11 profile showed the old thread map read
// at 64KB stride (2.4 TB/s, 63us). New map: wave-tile = 16 rows x one k64;
// an 8-lane group owns ONE row -> 256B contiguous read + full-128B-line
// write per row (XOR permutes within the line: sw = row&7 = lane>>3).
// ---------------------------------------------------------------------------
__global__ __launch_bounds__(256)
void convert_split_k(const float* __restrict__ nd, const float* __restrict__ gt,
                     _Float16* __restrict__ hi_t, _Float16* __restrict__ lo_t) {
  const int wt = blockIdx.x * 4 + (threadIdx.x >> 6);  // wave-tile 0..16383
  const int lane = threadIdx.x & 63;
  const int k64 = wt >> 6;         // 0..255
  const int rb = (wt & 63) << 4;   // row-block base (multiple of 16)
  const int g = lane & 7;
#pragma unroll
  for (int p = 0; p < 2; ++p) {
    const int row = rb + p * 8 + (lane >> 3);
    const float* __restrict__ src =
        (row < 512 ? nd + (size_t)row * HW : gt + (size_t)(row - 512) * HW) +
        k64 * 64 + g * 8;
    const float4 v0 = *(const float4*)(src);
    const float4 v1 = *(const float4*)(src + 4);
    const float x[8] = {v0.x, v0.y, v0.z, v0.w, v1.x, v1.y, v1.z, v1.w};
    f16x8 h, l;
#pragma unroll
    for (int j = 0; j < 8; ++j) {
      const float xs = x[j] * SCALE_F;
      const _Float16 hh = (_Float16)xs;
      h[j] = hh;
      l[j] = (_Float16)(xs - (float)hh);
    }
    const size_t o = ((size_t)k64 * 1024 + row) * 64 + (size_t)((g ^ (row & 7)) * 8);
    *(f16x8*)(hi_t + o) = h;
    *(f16x8*)(lo_t + o) = l;
  }
}

// ---------------------------------------------------------------------------
// Upper-triangle tiles (G symmetric). 128x128 tile, 8 waves (2x4), BK=64,
// 3-pass f16 split MFMA. T3 "2-phase" schedule: double-buffered 2x64KB LDS,
// ONE barrier per K-step (round 11: GEMM 77 -> ~28us).
// ---------------------------------------------------------------------------
#define STAGE(BUF, KT)                                                          \
  {                                                                             \
    const size_t tb_ = (size_t)(KT) * 65536;                                    \
    const size_t ga_ = tb_ + (size_t)ti * 8192 + w * 1024 + lane * 8;           \
    const size_t gb_ = tb_ + (size_t)tj * 8192 + w * 1024 + lane * 8;           \
    _Float16* lb_ = lds + (BUF) * 32768 + w * 1024;                             \
    __builtin_amdgcn_global_load_lds((gvoid_t*)(hi_t + ga_), (svoid_t*)(lb_), 16, 0, 0);                   \
    __builtin_amdgcn_global_load_lds((gvoid_t*)(hi_t + ga_ + 512), (svoid_t*)(lb_ + 512), 16, 0, 0);       \
    __builtin_amdgcn_global_load_lds((gvoid_t*)(lo_t + ga_), (svoid_t*)(lb_ + 8192), 16, 0, 0);            \
    __builtin_amdgcn_global_load_lds((gvoid_t*)(lo_t + ga_ + 512), (svoid_t*)(lb_ + 8704), 16, 0, 0);      \
    __builtin_amdgcn_global_load_lds((gvoid_t*)(hi_t + gb_), (svoid_t*)(lb_ + 16384), 16, 0, 0);           \
    __builtin_amdgcn_global_load_lds((gvoid_t*)(hi_t + gb_ + 512), (svoid_t*)(lb_ + 16896), 16, 0, 0);     \
    __builtin_amdgcn_global_load_lds((gvoid_t*)(lo_t + gb_), (svoid_t*)(lb_ + 24576), 16, 0, 0);           \
    __builtin_amdgcn_global_load_lds((gvoid_t*)(lo_t + gb_ + 512), (svoid_t*)(lb_ + 25088), 16, 0, 0);     \
  }

__global__ __launch_bounds__(512, 2)
void gemm_mfma_k(const _Float16* __restrict__ hi_t, const _Float16* __restrict__ lo_t,
                 float* __restrict__ part, int ns) {
  extern __shared__ _Float16 lds[];  // [2 buf][4 arr: Ahi,Alo,Bhi,Blo][8192]

  // bijective XCD-chunked swizzle (m204 form)
  const int nwg = NTILES * ns;
  const int b = blockIdx.x;
  const int k8 = b & 7, i8 = b >> 3;
  const int q8 = nwg >> 3, r8 = nwg & 7;
  const int start = (k8 < r8) ? k8 * (q8 + 1) : r8 * (q8 + 1) + (k8 - r8) * q8;
  const int lin = start + i8;
  const int c = lin / NTILES, tt = lin - c * NTILES;

  int ti, tj;
  tri_map(tt, ti, tj);
  const int q = 256 / ns, rm = 256 - q * ns;
  const int kt0 = c * q + (c < rm ? c : rm);
  const int nkt = q + (c < rm ? 1 : 0);
  const int t = threadIdx.x;
  const int lane = t & 63, w = t >> 6;  // 8 waves
  const int wr = w >> 2, wc = w & 3;    // 2 x 4 wave grid
  const int rlow = lane & 15, g0 = lane >> 4;
  const int sw = rlow & 7;

  f32x4 acc[4][2];
#pragma unroll
  for (int m = 0; m < 4; ++m)
#pragma unroll
    for (int n = 0; n < 2; ++n) acc[m][n] = (f32x4){0.f, 0.f, 0.f, 0.f};

  STAGE(0, kt0);
  __syncthreads();

  int cur = 0;
  for (int ks = 0; ks < nkt; ++ks) {
    if (ks + 1 < nkt) STAGE(cur ^ 1, kt0 + ks + 1);
    __builtin_amdgcn_sched_barrier(0);  // pin stages before reads/MFMA

    const _Float16* __restrict__ bb = lds + cur * 32768;
    f16x8 ah[2][4], al[2][4], bh[2][2], bl[2][2];
#pragma unroll
    for (int kk = 0; kk < 2; ++kk) {
      const int pe = ((kk * 4 + g0) ^ sw) * 8;
#pragma unroll
      for (int m = 0; m < 4; ++m) {
        const int ra = wr * 64 + m * 16 + rlow;
        ah[kk][m] = *(const f16x8*)(bb + ra * 64 + pe);
        al[kk][m] = *(const f16x8*)(bb + 8192 + ra * 64 + pe);
      }
#pragma unroll
      for (int n = 0; n < 2; ++n) {
        const int rb = wc * 32 + n * 16 + rlow;
        bh[kk][n] = *(const f16x8*)(bb + 16384 + rb * 64 + pe);
        bl[kk][n] = *(const f16x8*)(bb + 24576 + rb * 64 + pe);
      }
    }

    __builtin_amdgcn_s_setprio(1);
#pragma unroll
    for (int kk = 0; kk < 2; ++kk)
#pragma unroll
      for (int m = 0; m < 4; ++m)
#pragma unroll
        for (int n = 0; n < 2; ++n) {
          acc[m][n] = __builtin_amdgcn_mfma_f32_16x16x32_f16(ah[kk][m], bh[kk][n], acc[m][n], 0, 0, 0);
          acc[m][n] = __builtin_amdgcn_mfma_f32_16x16x32_f16(al[kk][m], bh[kk][n], acc[m][n], 0, 0, 0);
          acc[m][n] = __builtin_amdgcn_mfma_f32_16x16x32_f16(ah[kk][m], bl[kk][n], acc[m][n], 0, 0, 0);
        }
    __builtin_amdgcn_s_setprio(0);
    __syncthreads();  // drains stage (vmcnt0) + read-done for both buffers
    cur ^= 1;
  }

  // C/D layout: col = lane&15, row = (lane>>4)*4 + p (m89-verified)
  float* __restrict__ dst = part + ((size_t)c * NTILES + tt) * 16384;
  const int clb = wc * 32 + rlow;
  const int rlb = wr * 64 + g0 * 4;
#pragma unroll
  for (int m = 0; m < 4; ++m)
#pragma unroll
    for (int p = 0; p < 4; ++p) {
      const int rl = rlb + m * 16 + p;
#pragma unroll
      for (int n = 0; n < 2; ++n)
        dst[rl * 128 + clb + n * 16] = acc[m][n][p];
    }
}

// ---------------------------------------------------------------------------
// Sum split-K partials (fp64), unscale, write G tile + mirrored tile (LDS
// transpose), extract diagonal. Grid: 36 tiles x 16 slabs of 8 rows = 576.
// ---------------------------------------------------------------------------
__global__ __launch_bounds__(256)
void reduce_tiles_k(const float* __restrict__ part, float* __restrict__ G,
                    float* __restrict__ diag, int nsplit) {
  __shared__ float sl[8][129];
  const int blk = blockIdx.x;  // 0..575
  const int tt = blk >> 4, s = blk & 15;
  int ti, tj;
  tri_map(tt, ti, tj);
  const int t = threadIdx.x;
  const int base_in = tt * 16384 + s * 1024;

  float vals[4];
#pragma unroll
  for (int j = 0; j < 4; ++j) {
    const int idx = j * 256 + t;  // 0..1023 within slab
    double a = 0.0;
    for (int c = 0; c < nsplit; ++c)
      a += (double)part[(size_t)c * (NTILES * 16384) + base_in + idx];
    vals[j] = (float)(a * INV_SCALE2);
  }
#pragma unroll
  for (int j = 0; j < 4; ++j) {
    const int idx = j * 256 + t;
    const int r = idx >> 7, cl = idx & 127;
    const int R = ti * 128 + s * 8 + r, C = tj * 128 + cl;
    G[(size_t)R * NPTS + C] = vals[j];
    if (R == C) diag[R] = vals[j];
    sl[r][cl] = vals[j];
  }
  if (ti == tj) return;
  __syncthreads();
#pragma unroll
  for (int j = 0; j < 4; ++j) {
    const int idx = j * 256 + t;
    const int r = idx & 7, cl = idx >> 3;
    G[(size_t)(tj * 128 + cl) * NPTS + ti * 128 + s * 8 + r] = sl[r][cl];
  }
}

// ---------------------------------------------------------------------------
// One symmetric Sinkhorn phase: 512 blocks x 4 waves; 1 wave = 1 row-task.
// pot layout: [0]=f_ba, [1]=g_ab, [2]=f_aa, [3]=g_bb (512 doubles each).
// ---------------------------------------------------------------------------
__global__ __launch_bounds__(256)
void sinkhorn_phase_k(const float* __restrict__ G, const float* __restrict__ diag,
                      const double* __restrict__ src, double* __restrict__ dst,
                      double eps, double inv_eps, double damp, int use_pot,
                      int do_avg) {
  const int w = threadIdx.x >> 6, lane = threadIdx.x & 63;
  const int id = blockIdx.x * 4 + w;  // 0..2047
  const int which = id >> 9, r = id & 511;
  int row_pt, col_base, pot_idx;
  if (which == 0)      { row_pt = r;       col_base = 512; pot_idx = 1; }
  else if (which == 1) { row_pt = 512 + r; col_base = 0;   pot_idx = 0; }
  else if (which == 2) { row_pt = r;       col_base = 0;   pot_idx = 2; }
  else                 { row_pt = 512 + r; col_base = 512; pot_idx = 3; }

  const double dr = (double)diag[row_pt];
  const double* __restrict__ pot = src + pot_idx * 512;
  const float* __restrict__ Grow = G + (size_t)row_pt * NPTS + col_base;
  const float* __restrict__ dcol = diag + col_base;

  double arg[8];
  double m = -1.0e300;
#pragma unroll
  for (int u = 0; u < 8; ++u) {
    const int j = lane + u * 64;
    const double C = 0.5 * (dr + (double)dcol[j]) - (double)Grow[j];
    const double p = use_pot ? pot[j] : 0.0;
    const double a = (p - C) * inv_eps - LOG_N;
    arg[u] = a;
    m = fmax(m, a);
  }
#pragma unroll
  for (int off = 32; off > 0; off >>= 1) m = fmax(m, __shfl_xor(m, off));
  double s = 0.0;
#pragma unroll
  for (int u = 0; u < 8; ++u) s += exp(arg[u] - m);
#pragma unroll
  for (int off = 32; off > 0; off >>= 1) s += __shfl_xor(s, off);
  if (lane == 0) {
    const double lse = m + log(s);
    const double val = -eps * lse * damp;
    dst[which * 512 + r] = do_avg ? 0.5 * (src[which * 512 + r] + val) : val;
  }
}

// ---------------------------------------------------------------------------
// Debiased unbalanced Sinkhorn loss.
// ---------------------------------------------------------------------------
__global__ __launch_bounds__(256)
void loss_k(const double* __restrict__ pot, float* __restrict__ out, int out_size,
            double w) {
  const int t = threadIdx.x;
  double s = 0.0;
  for (int i = t; i < 512; i += 256) {
    s += (exp(-pot[1024 + i] / RHO_C) - exp(-pot[i] / RHO_C)) +
         (exp(-pot[1536 + i] / RHO_C) - exp(-pot[512 + i] / RHO_C));
  }
#pragma unroll
  for (int off = 32; off > 0; off >>= 1) s += __shfl_xor(s, off);
  __shared__ double wsum[4];
  if ((t & 63) == 0) wsum[t >> 6] = s;
  __syncthreads();
  if (t == 0) {
    out[0] = (float)(w * (wsum[0] + wsum[1] + wsum[2] + wsum[3]) * (1.0 / 512.0));
    for (int i = 1; i < out_size; ++i) out[i] = 0.f;
  }
}

extern "C" void kernel_launch(void* const* d_in, const int* in_sizes, int n_in,
                              void* d_out, int out_size, void* d_ws, size_t ws_size,
                              hipStream_t stream) {
  const float* nd = (const float*)d_in[1];
  const float* gt = (const float*)d_in[2];
  float* out = (float*)d_out;
  char* ws = (char*)d_ws;

  const size_t GM = (size_t)NPTS * NPTS;     // 1M elems
  const size_t P16 = (size_t)NPTS * HW * 2;  // 32 MB per half
  int nsplit = 7;                             // 36*7 = 252 blocks @ 1/CU: 1 round
  while (nsplit > 1 &&
         2 * P16 + (size_t)nsplit * NTILES * 16384 * 4 + GM * 4 + 65536 > ws_size)
    nsplit >>= 1;

  _Float16* hi_t = (_Float16*)ws;
  _Float16* lo_t = (_Float16*)(ws + P16);
  float* part = (float*)(ws + 2 * P16);
  const size_t partsz = (size_t)nsplit * NTILES * 16384 * 4;
  float* G = (float*)(ws + 2 * P16 + partsz);
  float* diag = (float*)(ws + 2 * P16 + partsz + GM * 4);
  double* pots = (double*)(ws + 2 * P16 + partsz + GM * 4 + 8192);

  hipFuncSetAttribute((const void*)gemm_mfma_k,
                      hipFuncAttributeMaxDynamicSharedMemorySize, 131072);

  convert_split_k<<<4096, 256, 0, stream>>>(nd, gt, hi_t, lo_t);
  gemm_mfma_k<<<NTILES * nsplit, 512, 131072, stream>>>(hi_t, lo_t, part, nsplit);
  reduce_tiles_k<<<576, 256, 0, stream>>>(part, G, diag, nsplit);

  const double eps_list[9] = {1.0, 1.0, 0.25, 0.0625, 0.015625,
                              0.00390625, 0.0009765625, 0.000244140625, 1e-4};
  double* p0 = pots;
  double* p1 = pots + 2048;
  {  // init at eps0 = 1.0, no inner potentials, no averaging
    const double eps = 1.0, d = 1.0 / (1.0 + eps / RHO_C);
    sinkhorn_phase_k<<<512, 256, 0, stream>>>(G, diag, p1, p0, eps, 1.0 / eps, d, 0, 0);
  }
  double* src = p0;
  double* dst = p1;
  for (int k = 0; k < 9; ++k) {  // symmetric averaged updates
    const double eps = eps_list[k], d = 1.0 / (1.0 + eps / RHO_C);
    sinkhorn_phase_k<<<512, 256, 0, stream>>>(G, diag, src, dst, eps, 1.0 / eps, d, 1, 1);
    double* tmp = src; src = dst; dst = tmp;
  }
  {  // final extrapolation at blur^2, no averaging
    const double eps = 1e-4, d = 1.0 / (1.0 + eps / RHO_C);
    sinkhorn_phase_k<<<512, 256, 0, stream>>>(G, diag, src, dst, eps, 1.0 / eps, d, 1, 0);
    double* tmp = src; src = dst; dst = tmp;
  }
  loss_k<<<1, 256, 0, stream>>>(src, out, out_size, RHO_C + 1e-4 * 0.5);
}

// Round 13
// 139.082 us; speedup vs baseline: 1.4763x; 1.0130x over previous
//
#include <hip/hip_runtime.h>
#include <math.h>

#define HW 16384
#define NPTS 1024
#define LOG_N 6.2383246250395075
#define RHO_C 0.09
#define SCALE_F 16384.0f
#define INV_SCALE2 3.725290298461914e-09  // 2^-28, exact
#define NTILES 36                          // 8x8 upper triangle

typedef _Float16 f16x8 __attribute__((ext_vector_type(8)));
typedef float f32x4 __attribute__((ext_vector_type(4)));

typedef __attribute__((address_space(1))) const void gvoid_t;
typedef __attribute__((address_space(3))) void svoid_t;

__device__ __forceinline__ void tri_map(int tt, int& ti, int& tj) {
  int a = 0, r = tt;
  while (r >= 8 - a) { r -= 8 - a; ++a; }
  ti = a; tj = a + r;
}

// ---------------------------------------------------------------------------
// Convert fp32 P=[nd;gt] (1024 x 16384) into scaled fp16 hi/lo split, stored
// K-tiled: hi_t[k64][row][64], groups pre-swizzled by g ^ (row&7) (GEMM's
// conflict-free LDS image). Wave-tile = 16 rows x one k64; an 8-lane group
// owns ONE row -> 256B contiguous read + full-128B-line write per row.
// ---------------------------------------------------------------------------
__global__ __launch_bounds__(256)
void convert_split_k(const float* __restrict__ nd, const float* __restrict__ gt,
                     _Float16* __restrict__ hi_t, _Float16* __restrict__ lo_t) {
  const int wt = blockIdx.x * 4 + (threadIdx.x >> 6);  // wave-tile 0..16383
  const int lane = threadIdx.x & 63;
  const int k64 = wt >> 6;         // 0..255
  const int rb = (wt & 63) << 4;   // row-block base (multiple of 16)
  const int g = lane & 7;
#pragma unroll
  for (int p = 0; p < 2; ++p) {
    const int row = rb + p * 8 + (lane >> 3);
    const float* __restrict__ src =
        (row < 512 ? nd + (size_t)row * HW : gt + (size_t)(row - 512) * HW) +
        k64 * 64 + g * 8;
    const float4 v0 = *(const float4*)(src);
    const float4 v1 = *(const float4*)(src + 4);
    const float x[8] = {v0.x, v0.y, v0.z, v0.w, v1.x, v1.y, v1.z, v1.w};
    f16x8 h, l;
#pragma unroll
    for (int j = 0; j < 8; ++j) {
      const float xs = x[j] * SCALE_F;
      const _Float16 hh = (_Float16)xs;
      h[j] = hh;
      l[j] = (_Float16)(xs - (float)hh);
    }
    const size_t o = ((size_t)k64 * 1024 + row) * 64 + (size_t)((g ^ (row & 7)) * 8);
    *(f16x8*)(hi_t + o) = h;
    *(f16x8*)(lo_t + o) = l;
  }
}

// ---------------------------------------------------------------------------
// Upper-triangle tiles (G symmetric). 128x128 tile, 8 waves, BK=64, 3-pass
// f16 split MFMA, T3 2-phase dbuf LDS schedule (1 barrier/K-step).
// WAVE-PAIR K-SPLIT (round 13): 8 waves = 4 pair-tiles (2x2 grid of 64x64)
// x 2 K-halves; wave w does kk-slice h=w>>2 of pair (pr,pc). Fragment reads
// drop 192->128 KB/K-step (B/FLOP: wave tile 64x32 -> 64x64) so LDS (1536c)
// balances MFMA (1549c). Pair halves summed via LDS in the epilogue.
// Diagonal tiles (ti==tj) skip B-staging and read the A image.
// ---------------------------------------------------------------------------
__global__ __launch_bounds__(512, 2)
void gemm_mfma_k(const _Float16* __restrict__ hi_t, const _Float16* __restrict__ lo_t,
                 float* __restrict__ part, int ns) {
  extern __shared__ _Float16 lds[];  // [2 buf][Ahi,Alo,Bhi,Blo][8192]

  // bijective XCD-chunked swizzle (m204 form)
  const int nwg = NTILES * ns;
  const int b = blockIdx.x;
  const int k8 = b & 7, i8 = b >> 3;
  const int q8 = nwg >> 3, r8 = nwg & 7;
  const int start = (k8 < r8) ? k8 * (q8 + 1) : r8 * (q8 + 1) + (k8 - r8) * q8;
  const int lin = start + i8;
  const int c = lin / NTILES, tt = lin - c * NTILES;

  int ti, tj;
  tri_map(tt, ti, tj);
  const bool dtile = (ti == tj);
  const int q = 256 / ns, rm = 256 - q * ns;
  const int kt0 = c * q + (c < rm ? c : rm);
  const int nkt = q + (c < rm ? 1 : 0);
  const int t = threadIdx.x;
  const int lane = t & 63, w = t >> 6;       // 8 waves
  const int pr = (w >> 1) & 1, pc = w & 1;   // pair tile (64x64) coords
  const int h = w >> 2;                      // K-half: kk slice index
  const int rlow = lane & 15, g0 = lane >> 4;
  const int sw = rlow & 7;
  const int boff = dtile ? 0 : 16384;        // B reads alias A image on diagonal

  f32x4 acc[4][4];
#pragma unroll
  for (int m = 0; m < 4; ++m)
#pragma unroll
    for (int n = 0; n < 4; ++n) acc[m][n] = (f32x4){0.f, 0.f, 0.f, 0.f};

#define STAGE(BUF, KT)                                                          \
  {                                                                             \
    const size_t tb_ = (size_t)(KT) * 65536;                                    \
    const size_t ga_ = tb_ + (size_t)ti * 8192 + w * 1024 + lane * 8;           \
    _Float16* lb_ = lds + (BUF) * 32768 + w * 1024;                             \
    __builtin_amdgcn_global_load_lds((gvoid_t*)(hi_t + ga_), (svoid_t*)(lb_), 16, 0, 0);               \
    __builtin_amdgcn_global_load_lds((gvoid_t*)(hi_t + ga_ + 512), (svoid_t*)(lb_ + 512), 16, 0, 0);   \
    __builtin_amdgcn_global_load_lds((gvoid_t*)(lo_t + ga_), (svoid_t*)(lb_ + 8192), 16, 0, 0);        \
    __builtin_amdgcn_global_load_lds((gvoid_t*)(lo_t + ga_ + 512), (svoid_t*)(lb_ + 8704), 16, 0, 0);  \
    if (!dtile) {                                                               \
      const size_t gb_ = tb_ + (size_t)tj * 8192 + w * 1024 + lane * 8;         \
      __builtin_amdgcn_global_load_lds((gvoid_t*)(hi_t + gb_), (svoid_t*)(lb_ + 16384), 16, 0, 0);     \
      __builtin_amdgcn_global_load_lds((gvoid_t*)(hi_t + gb_ + 512), (svoid_t*)(lb_ + 16896), 16, 0, 0);\
      __builtin_amdgcn_global_load_lds((gvoid_t*)(lo_t + gb_), (svoid_t*)(lb_ + 24576), 16, 0, 0);     \
      __builtin_amdgcn_global_load_lds((gvoid_t*)(lo_t + gb_ + 512), (svoid_t*)(lb_ + 25088), 16, 0, 0);\
    }                                                                           \
  }

  STAGE(0, kt0);
  __syncthreads();

  int cur = 0;
  for (int ks = 0; ks < nkt; ++ks) {
    if (ks + 1 < nkt) STAGE(cur ^ 1, kt0 + ks + 1);
    __builtin_amdgcn_sched_barrier(0);  // pin stages before reads/MFMA

    const _Float16* __restrict__ bb = lds + cur * 32768;
    const int pe = ((h * 4 + g0) ^ sw) * 8;
    f16x8 ah[4], al[4], bh[4], bl[4];
#pragma unroll
    for (int m = 0; m < 4; ++m) {
      const int ra = pr * 64 + m * 16 + rlow;
      ah[m] = *(const f16x8*)(bb + ra * 64 + pe);
      al[m] = *(const f16x8*)(bb + 8192 + ra * 64 + pe);
      const int rb = pc * 64 + m * 16 + rlow;
      bh[m] = *(const f16x8*)(bb + boff + rb * 64 + pe);
      bl[m] = *(const f16x8*)(bb + boff + 8192 + rb * 64 + pe);
    }

    __builtin_amdgcn_s_setprio(1);
#pragma unroll
    for (int m = 0; m < 4; ++m)
#pragma unroll
      for (int n = 0; n < 4; ++n) {
        acc[m][n] = __builtin_amdgcn_mfma_f32_16x16x32_f16(ah[m], bh[n], acc[m][n], 0, 0, 0);
        acc[m][n] = __builtin_amdgcn_mfma_f32_16x16x32_f16(al[m], bh[n], acc[m][n], 0, 0, 0);
        acc[m][n] = __builtin_amdgcn_mfma_f32_16x16x32_f16(ah[m], bl[n], acc[m][n], 0, 0, 0);
      }
    __builtin_amdgcn_s_setprio(0);
    __syncthreads();  // drains stage + read-done for both buffers
    cur ^= 1;
  }

  // Pair-sum epilogue: K-half h=1 dumps acc to LDS; h=0 adds and writes C.
  float* red = (float*)lds;  // 4 pairs x 16KB, LDS is free after the loop
  if (h == 1) {
    float* wb = red + (w & 3) * 4096;
#pragma unroll
    for (int m = 0; m < 4; ++m)
#pragma unroll
      for (int n = 0; n < 4; ++n)
        *(f32x4*)(wb + (m * 4 + n) * 256 + lane * 4) = acc[m][n];
  }
  __syncthreads();
  if (h == 0) {
    float* wb = red + w * 4096;  // w in 0..3 == pair id
    float* __restrict__ dst = part + ((size_t)c * NTILES + tt) * 16384;
    const int clb = pc * 64 + rlow;
    const int rlb = pr * 64 + g0 * 4;
#pragma unroll
    for (int m = 0; m < 4; ++m)
#pragma unroll
      for (int n = 0; n < 4; ++n) {
        const f32x4 o = *(const f32x4*)(wb + (m * 4 + n) * 256 + lane * 4);
        const f32x4 s = acc[m][n] + o;
#pragma unroll
        for (int p = 0; p < 4; ++p)
          dst[(rlb + m * 16 + p) * 128 + clb + n * 16] = s[p];
      }
  }
#undef STAGE
}

// ---------------------------------------------------------------------------
// Sum split-K partials (fp64), unscale, write G tile + mirrored tile (LDS
// transpose), extract diagonal. Grid: 36 tiles x 16 slabs of 8 rows = 576.
// ---------------------------------------------------------------------------
__global__ __launch_bounds__(256)
void reduce_tiles_k(const float* __restrict__ part, float* __restrict__ G,
                    float* __restrict__ diag, int nsplit) {
  __shared__ float sl[8][129];
  const int blk = blockIdx.x;  // 0..575
  const int tt = blk >> 4, s = blk & 15;
  int ti, tj;
  tri_map(tt, ti, tj);
  const int t = threadIdx.x;
  const int base_in = tt * 16384 + s * 1024;

  float vals[4];
#pragma unroll
  for (int j = 0; j < 4; ++j) {
    const int idx = j * 256 + t;  // 0..1023 within slab
    double a = 0.0;
    for (int c = 0; c < nsplit; ++c)
      a += (double)part[(size_t)c * (NTILES * 16384) + base_in + idx];
    vals[j] = (float)(a * INV_SCALE2);
  }
#pragma unroll
  for (int j = 0; j < 4; ++j) {
    const int idx = j * 256 + t;
    const int r = idx >> 7, cl = idx & 127;
    const int R = ti * 128 + s * 8 + r, C = tj * 128 + cl;
    G[(size_t)R * NPTS + C] = vals[j];
    if (R == C) diag[R] = vals[j];
    sl[r][cl] = vals[j];
  }
  if (ti == tj) return;
  __syncthreads();
#pragma unroll
  for (int j = 0; j < 4; ++j) {
    const int idx = j * 256 + t;
    const int r = idx & 7, cl = idx >> 3;
    G[(size_t)(tj * 128 + cl) * NPTS + ti * 128 + s * 8 + r] = sl[r][cl];
  }
}

// ---------------------------------------------------------------------------
// One symmetric Sinkhorn phase: 512 blocks x 4 waves; 1 wave = 1 row-task.
// pot layout: [0]=f_ba, [1]=g_ab, [2]=f_aa, [3]=g_bb (512 doubles each).
// ---------------------------------------------------------------------------
__global__ __launch_bounds__(256)
void sinkhorn_phase_k(const float* __restrict__ G, const float* __restrict__ diag,
                      const double* __restrict__ src, double* __restrict__ dst,
                      double eps, double inv_eps, double damp, int use_pot,
                      int do_avg) {
  const int w = threadIdx.x >> 6, lane = threadIdx.x & 63;
  const int id = blockIdx.x * 4 + w;  // 0..2047
  const int which = id >> 9, r = id & 511;
  int row_pt, col_base, pot_idx;
  if (which == 0)      { row_pt = r;       col_base = 512; pot_idx = 1; }
  else if (which == 1) { row_pt = 512 + r; col_base = 0;   pot_idx = 0; }
  else if (which == 2) { row_pt = r;       col_base = 0;   pot_idx = 2; }
  else                 { row_pt = 512 + r; col_base = 512; pot_idx = 3; }

  const double dr = (double)diag[row_pt];
  const double* __restrict__ pot = src + pot_idx * 512;
  const float* __restrict__ Grow = G + (size_t)row_pt * NPTS + col_base;
  const float* __restrict__ dcol = diag + col_base;

  double arg[8];
  double m = -1.0e300;
#pragma unroll
  for (int u = 0; u < 8; ++u) {
    const int j = lane + u * 64;
    const double C = 0.5 * (dr + (double)dcol[j]) - (double)Grow[j];
    const double p = use_pot ? pot[j] : 0.0;
    const double a = (p - C) * inv_eps - LOG_N;
    arg[u] = a;
    m = fmax(m, a);
  }
#pragma unroll
  for (int off = 32; off > 0; off >>= 1) m = fmax(m, __shfl_xor(m, off));
  double s = 0.0;
#pragma unroll
  for (int u = 0; u < 8; ++u) s += exp(arg[u] - m);
#pragma unroll
  for (int off = 32; off > 0; off >>= 1) s += __shfl_xor(s, off);
  if (lane == 0) {
    const double lse = m + log(s);
    const double val = -eps * lse * damp;
    dst[which * 512 + r] = do_avg ? 0.5 * (src[which * 512 + r] + val) : val;
  }
}

// ---------------------------------------------------------------------------
// Debiased unbalanced Sinkhorn loss.
// ---------------------------------------------------------------------------
__global__ __launch_bounds__(256)
void loss_k(const double* __restrict__ pot, float* __restrict__ out, int out_size,
            double w) {
  const int t = threadIdx.x;
  double s = 0.0;
  for (int i = t; i < 512; i += 256) {
    s += (exp(-pot[1024 + i] / RHO_C) - exp(-pot[i] / RHO_C)) +
         (exp(-pot[1536 + i] / RHO_C) - exp(-pot[512 + i] / RHO_C));
  }
#pragma unroll
  for (int off = 32; off > 0; off >>= 1) s += __shfl_xor(s, off);
  __shared__ double wsum[4];
  if ((t & 63) == 0) wsum[t >> 6] = s;
  __syncthreads();
  if (t == 0) {
    out[0] = (float)(w * (wsum[0] + wsum[1] + wsum[2] + wsum[3]) * (1.0 / 512.0));
    for (int i = 1; i < out_size; ++i) out[i] = 0.f;
  }
}

extern "C" void kernel_launch(void* const* d_in, const int* in_sizes, int n_in,
                              void* d_out, int out_size, void* d_ws, size_t ws_size,
                              hipStream_t stream) {
  const float* nd = (const float*)d_in[1];
  const float* gt = (const float*)d_in[2];
  float* out = (float*)d_out;
  char* ws = (char*)d_ws;

  const size_t GM = (size_t)NPTS * NPTS;     // 1M elems
  const size_t P16 = (size_t)NPTS * HW * 2;  // 32 MB per half
  int nsplit = 7;                             // 36*7 = 252 blocks @ 1/CU: 1 round
  while (nsplit > 1 &&
         2 * P16 + (size_t)nsplit * NTILES * 16384 * 4 + GM * 4 + 65536 > ws_size)
    nsplit >>= 1;

  _Float16* hi_t = (_Float16*)ws;
  _Float16* lo_t = (_Float16*)(ws + P16);
  float* part = (float*)(ws + 2 * P16);
  const size_t partsz = (size_t)nsplit * NTILES * 16384 * 4;
  float* G = (float*)(ws + 2 * P16 + partsz);
  float* diag = (float*)(ws + 2 * P16 + partsz + GM * 4);
  double* pots = (double*)(ws + 2 * P16 + partsz + GM * 4 + 8192);

  hipFuncSetAttribute((const void*)gemm_mfma_k,
                      hipFuncAttributeMaxDynamicSharedMemorySize, 131072);

  convert_split_k<<<4096, 256, 0, stream>>>(nd, gt, hi_t, lo_t);
  gemm_mfma_k<<<NTILES * nsplit, 512, 131072, stream>>>(hi_t, lo_t, part, nsplit);
  reduce_tiles_k<<<576, 256, 0, stream>>>(part, G, diag, nsplit);

  const double eps_list[9] = {1.0, 1.0, 0.25, 0.0625, 0.015625,
                              0.00390625, 0.0009765625, 0.000244140625, 1e-4};
  double* p0 = pots;
  double* p1 = pots + 2048;
  {  // init at eps0 = 1.0, no inner potentials, no averaging
    const double eps = 1.0, d = 1.0 / (1.0 + eps / RHO_C);
    sinkhorn_phase_k<<<512, 256, 0, stream>>>(G, diag, p1, p0, eps, 1.0 / eps, d, 0, 0);
  }
  double* src = p0;
  double* dst = p1;
  for (int k = 0; k < 9; ++k) {  // symmetric averaged updates
    const double eps = eps_list[k], d = 1.0 / (1.0 + eps / RHO_C);
    sinkhorn_phase_k<<<512, 256, 0, stream>>>(G, diag, src, dst, eps, 1.0 / eps, d, 1, 1);
    double* tmp = src; src = dst; dst = tmp;
  }
  {  // final extrapolation at blur^2, no averaging
    const double eps = 1e-4, d = 1.0 / (1.0 + eps / RHO_C);
    sinkhorn_phase_k<<<512, 256, 0, stream>>>(G, diag, src, dst, eps, 1.0 / eps, d, 1, 0);
    double* tmp = src; src = dst; dst = tmp;
  }
  loss_k<<<1, 256, 0, stream>>>(src, out, out_size, RHO_C + 1e-4 * 0.5);
}